// Round 16
// baseline (235.631 us; speedup 1.0000x reference)
//
#include <hip/hip_runtime.h>
#include <hip/hip_bf16.h>
#include <math.h>

#define B_ 8
#define N_ 4096
#define C_ 256
#define H_ 8
#define HD_ 32
#define BN_ (B_ * N_)  // 32768
#define E_ ((size_t)BN_ * C_)  // 8388608

typedef __attribute__((ext_vector_type(8))) short short8;
typedef __attribute__((ext_vector_type(4))) float f32x4;

__device__ __forceinline__ float b2f(__hip_bfloat16 x) { return __bfloat162float(x); }

__device__ __forceinline__ void gl_lds16(const void* gp, void* lp) {
    __builtin_amdgcn_global_load_lds(
        (const __attribute__((address_space(1))) unsigned int*)gp,
        (__attribute__((address_space(3))) unsigned int*)lp,
        16, 0, 0);
}

// raw v_log_f32 / v_exp_f32 (base-2), no ocml fixup
__device__ __forceinline__ float fast_abspow(float v, float p) {
    float av = fabsf(v);
    return (av > 0.f) ? __builtin_amdgcn_exp2f(p * __builtin_amdgcn_logf(av)) : 0.f;
}

__device__ __forceinline__ float bf_lo(unsigned u) { return __uint_as_float(u << 16); }
__device__ __forceinline__ float bf_hi(unsigned u) { return __uint_as_float(u & 0xffff0000u); }
__device__ __forceinline__ unsigned short f2bfbits(float f) {
    __hip_bfloat16 h = __float2bfloat16(f);
    return *(unsigned short*)&h;
}
__device__ __forceinline__ unsigned pack2(float lo, float hi) {
    return (unsigned)f2bfbits(lo) | ((unsigned)f2bfbits(hi) << 16);
}

// ---- merged converts: blocks [0,4096): x -> bf16 (vectorized); [4096,4177): weights+powers;
// ----                  blocks [4177, 4241): zero kv_mat2 (for atomic accumulation) ----
__global__ __launch_bounds__(256) void cvt_all(
    const float* __restrict__ x, const float* __restrict__ Wqg,
    const float* __restrict__ Wkv, const float* __restrict__ Wp,
    const float* __restrict__ pp,
    __hip_bfloat16* __restrict__ xb, __hip_bfloat16* __restrict__ Wt1,
    __hip_bfloat16* __restrict__ Wt2, float* __restrict__ powers,
    float* __restrict__ kv_mat2)
{
    int t = threadIdx.x;
    int bid0 = blockIdx.x;
    if (bid0 < 4096) {
        size_t i = ((size_t)bid0 * 256 + t) * 8;
        float4 a = *(const float4*)&x[i];
        float4 b = *(const float4*)&x[i + 4];
        uint4 o = {pack2(a.x, a.y), pack2(a.z, a.w), pack2(b.x, b.y), pack2(b.z, b.w)};
        *(uint4*)&xb[i] = o;
        return;
    }
    int bid = bid0 - 4096;
    if (bid == 80) {
        powers[t] = 1.0f + 4.0f / (1.0f + expf(-pp[t]));
        return;
    }
    if (bid >= 81) {
        ((float4*)kv_mat2)[(size_t)(bid - 81) * 256 + t] = (float4){0.f, 0.f, 0.f, 0.f};
        return;
    }
    __shared__ float tile[64][65];
    const float* src;
    __hip_bfloat16* dst;
    int scols, tr, tc, dn0;
    if (bid < 32)      { src = Wqg; scols = 512; tr = bid >> 3;        tc = bid & 7;        dst = Wt1; dn0 = tc * 64; }
    else if (bid < 64) { src = Wkv; scols = 512; tr = (bid - 32) >> 3; tc = (bid - 32) & 7; dst = Wt1; dn0 = 512 + tc * 64; }
    else               { src = Wp;  scols = 256; tr = (bid - 64) >> 2; tc = (bid - 64) & 3; dst = Wt2; dn0 = tc * 64; }
    int tx = t & 63, ty = t >> 6;
    #pragma unroll
    for (int i = 0; i < 16; i++) {
        int r = ty + i * 4;
        tile[r][tx] = src[(size_t)(tr * 64 + r) * scols + tc * 64 + tx];
    }
    __syncthreads();
    #pragma unroll
    for (int i = 0; i < 16; i++) {
        int n_local = ty + i * 4;
        dst[(size_t)(dn0 + n_local) * 256 + tr * 64 + tx] = __float2bfloat16(tile[tx][n_local]);
    }
}

// ---- GEMM1 v7: 128x256 tile (one full region per block), grid 1024, BK=64 single-buffer.
// Rationale (R15 PMC: MfmaUtil 13%, VALUBusy 29%): raise MFMA per staged byte.
// Per wave per K-step: 64 MFMAs (4m x 8n x 2kh) vs 16 before; A re-fetched by 4
// col-panels instead of 8; per-MFMA addressing halves. R8-proven 64-short-row XOR
// swizzle (read chunk' = (kh*4+quad) ^ (row&7); source chunk (l&7)^(l>>3), dest linear).
// LDS 48KB (As 16K + Bs 32K); epilogue restages C through first 32KB in two col-halves. ----
__global__ __launch_bounds__(256) void gemm1_mfma(
    const __hip_bfloat16* __restrict__ xb, const __hip_bfloat16* __restrict__ Wt1,
    const float* __restrict__ powers,
    __hip_bfloat16* __restrict__ q16, __hip_bfloat16* __restrict__ k16,
    __hip_bfloat16* __restrict__ g16, __hip_bfloat16* __restrict__ v16)
{
    __shared__ __align__(16) unsigned short ABs[128 * 64 + 256 * 64];  // 49152 B
    unsigned short* As = ABs;
    unsigned short* Bs = ABs + 128 * 64;
    int t = threadIdx.x;
    int w = t >> 6, l = t & 63;
    // XCD swizzle: nwg=1024, 8 XCDs, 128 blocks/chunk (bijective)
    int bswz = (blockIdx.x & 7) * 128 + (blockIdx.x >> 3);
    int row0 = (bswz >> 2) * 128;
    int cp = bswz & 3;            // region: 0:q 1:g 2:k 3:v
    int col0 = cp * 256;          // Wt1 row-panel base
    int wm = (w >> 1) * 64, wn = (w & 1) * 128;
    int lane15 = l & 15, quad = l >> 4;
    int sr8 = l >> 3;
    int sc = ((l & 7) ^ sr8) * 8;
    int r7 = lane15 & 7;

    f32x4 acc[4][8];
    #pragma unroll
    for (int mi = 0; mi < 4; mi++)
        #pragma unroll
        for (int ni = 0; ni < 8; ni++) acc[mi][ni] = (f32x4){0.f, 0.f, 0.f, 0.f};

    for (int k0 = 0; k0 < 256; k0 += 64) {
        #pragma unroll
        for (int j = 0; j < 4; j++) {
            int rowl = j * 32 + w * 8 + sr8;
            gl_lds16(&xb[(size_t)(row0 + rowl) * 256 + k0 + sc],
                     &As[(j * 32 + w * 8) * 64]);
        }
        #pragma unroll
        for (int j = 0; j < 8; j++) {
            int rowl = j * 32 + w * 8 + sr8;
            gl_lds16(&Wt1[(size_t)(col0 + rowl) * 256 + k0 + sc],
                     &Bs[(j * 32 + w * 8) * 64]);
        }
        __syncthreads();
        #pragma unroll
        for (int kh = 0; kh < 2; kh++) {
            int cs_k = ((kh * 4 + quad) ^ r7) * 8;
            short8 a[4], b[8];
            #pragma unroll
            for (int mi = 0; mi < 4; mi++)
                a[mi] = *(const short8*)&As[(wm + mi * 16 + lane15) * 64 + cs_k];
            #pragma unroll
            for (int ni = 0; ni < 8; ni++)
                b[ni] = *(const short8*)&Bs[(wn + ni * 16 + lane15) * 64 + cs_k];
            #pragma unroll
            for (int mi = 0; mi < 4; mi++)
                #pragma unroll
                for (int ni = 0; ni < 8; ni++)
                    acc[mi][ni] = __builtin_amdgcn_mfma_f32_16x16x32_bf16(a[mi], b[ni], acc[mi][ni], 0, 0, 0);
        }
        __syncthreads();
    }

    bool dopow = (cp == 0) || (cp == 2);
    __hip_bfloat16* dst = (cp == 0) ? q16 : (cp == 1) ? g16 : (cp == 2) ? k16 : v16;
    // two col-half epilogues through the first 32KB (C-stage [128][128] bf16, XOR-nibble swz)
    #pragma unroll
    for (int ch = 0; ch < 2; ch++) {
        if ((w & 1) == ch) {
            #pragma unroll
            for (int mi = 0; mi < 4; mi++) {
                #pragma unroll
                for (int ni = 0; ni < 8; ni++) {
                    int rowb = wm + mi * 16 + quad * 4;
                    int collF = wn + ni * 16 + lane15;   // 0..255 (wn == ch*128 for these waves)
                    int coll = collF - ch * 128;         // 0..127 within half
                    float p = powers[collF];
                    int cchunk = coll >> 3, cin = coll & 7;
                    #pragma unroll
                    for (int r = 0; r < 4; r++) {
                        int rl = rowb + r;
                        float v = acc[mi][ni][r];
                        float o = dopow ? fast_abspow(v, p) : v;
                        ABs[rl * 128 + ((cchunk ^ (rl & 15)) << 3) + cin] = f2bfbits(o);
                    }
                }
            }
        }
        __syncthreads();
        #pragma unroll
        for (int j = 0; j < 8; j++) {
            int g = j * 256 + t;
            int rl = g >> 4, chunk = g & 15;
            uint4 vv = *(const uint4*)&ABs[rl * 128 + ((chunk ^ (rl & 15)) << 3)];
            *(uint4*)&dst[(size_t)(row0 + rl) * 256 + ch * 128 + chunk * 8] = vv;
        }
        __syncthreads();
    }
}

// ---- fused kvmat_mfma (blocks 0..511) + depthwise conv (blocks 512..2559) (R9-exact) ----
__global__ __launch_bounds__(256) void kvconv_kernel(
    const __hip_bfloat16* __restrict__ k16, const __hip_bfloat16* __restrict__ v16,
    float* __restrict__ kv_mat2,
    const float* __restrict__ w, const float* __restrict__ bias,
    __hip_bfloat16* __restrict__ vloc)
{
    __shared__ __align__(16) unsigned char smraw[18560];
    int t = threadIdx.x;

    if (blockIdx.x < 512) {
        unsigned short (*KV)[32][136] = (unsigned short (*)[32][136])smraw;  // 17408 B
        int w_ = t >> 6, l = t & 63;
        int lane15 = l & 15, quad = l >> 4;
        int bid = blockIdx.x;
        int pair = bid >> 3, seg = bid & 7;
        int b = pair >> 3, h = pair & 7;
        int nloc = t & 127, cs = (t >> 7) * 16;

        f32x4 acc[2][2];
        #pragma unroll
        for (int di = 0; di < 2; di++)
            #pragma unroll
            for (int ei = 0; ei < 2; ei++) acc[di][ei] = (f32x4){0.f, 0.f, 0.f, 0.f};

        const size_t base = (size_t)b * N_ * 256 + h * 32 + cs;
        for (int c4 = 0; c4 < 4; c4++) {
            int n0 = seg * 512 + c4 * 128;
            const uint4* kp = (const uint4*)(k16 + base + (size_t)(n0 + nloc) * 256);
            uint4 ka = kp[0], kb = kp[1];
            const uint4* vp = (const uint4*)(v16 + base + (size_t)(n0 + nloc) * 256);
            uint4 va = vp[0], vb = vp[1];
            __syncthreads();
            unsigned kw[8] = {ka.x, ka.y, ka.z, ka.w, kb.x, kb.y, kb.z, kb.w};
            unsigned vw[8] = {va.x, va.y, va.z, va.w, vb.x, vb.y, vb.z, vb.w};
            #pragma unroll
            for (int j = 0; j < 8; j++) {
                KV[0][cs + 2 * j][nloc]     = (unsigned short)(kw[j] & 0xffffu);
                KV[0][cs + 2 * j + 1][nloc] = (unsigned short)(kw[j] >> 16);
                KV[1][cs + 2 * j][nloc]     = (unsigned short)(vw[j] & 0xffffu);
                KV[1][cs + 2 * j + 1][nloc] = (unsigned short)(vw[j] >> 16);
            }
            __syncthreads();
            int nb = w_ * 32 + quad * 8;
            short8 a[2], bb[2];
            #pragma unroll
            for (int di = 0; di < 2; di++)
                a[di] = *(const short8*)&KV[0][di * 16 + lane15][nb];
            #pragma unroll
            for (int ei = 0; ei < 2; ei++)
                bb[ei] = *(const short8*)&KV[1][ei * 16 + lane15][nb];
            #pragma unroll
            for (int di = 0; di < 2; di++)
                #pragma unroll
                for (int ei = 0; ei < 2; ei++)
                    acc[di][ei] = __builtin_amdgcn_mfma_f32_16x16x32_bf16(a[di], bb[ei], acc[di][ei], 0, 0, 0);
        }

        __syncthreads();
        float* red = (float*)smraw;  // [4][32][33] f32 = 16896 B
        #pragma unroll
        for (int di = 0; di < 2; di++)
            #pragma unroll
            for (int ei = 0; ei < 2; ei++) {
                int e = ei * 16 + lane15;
                #pragma unroll
                for (int r = 0; r < 4; r++) {
                    int d = di * 16 + quad * 4 + r;
                    red[w_ * 1056 + e * 33 + d] = acc[di][ei][r];
                }
            }
        __syncthreads();
        #pragma unroll
        for (int j = 0; j < 4; j++) {
            int o = j * 256 + t;
            int e = o >> 5, d = o & 31;
            float s = red[e * 33 + d] + red[1056 + e * 33 + d]
                    + red[2112 + e * 33 + d] + red[3168 + e * 33 + d];
            atomicAdd(&kv_mat2[(size_t)b * 8192 + e * 256 + h * 32 + d], s);
        }
        return;
    }

    // ---- depthwise 5x5 conv body ----
    float* img = (float*)smraw;                  // 64*72 floats = 18432 B
    float* wl  = (float*)(smraw + 18432);        // 25 floats
    int gid = blockIdx.x - 512;
    int DD = gid & 31;
    if (t < 128) {
        int row = t >> 1, side = (t & 1) * 68;
        *(float4*)&img[row * 72 + side] = (float4){0.f, 0.f, 0.f, 0.f};
    }
    if (t < 25) wl[t] = w[DD * 25 + t];
    {
        int row = t >> 2, colb = (t & 3) * 16;
        const uint4* src = (const uint4*)(v16 + (size_t)gid * 4096 + row * 64 + colb);
        uint4 u0 = src[0], u1 = src[1];
        float4* d = (float4*)&img[row * 72 + 4 + colb];
        d[0] = (float4){bf_lo(u0.x), bf_hi(u0.x), bf_lo(u0.y), bf_hi(u0.y)};
        d[1] = (float4){bf_lo(u0.z), bf_hi(u0.z), bf_lo(u0.w), bf_hi(u0.w)};
        d[2] = (float4){bf_lo(u1.x), bf_hi(u1.x), bf_lo(u1.y), bf_hi(u1.y)};
        d[3] = (float4){bf_lo(u1.z), bf_hi(u1.z), bf_lo(u1.w), bf_hi(u1.w)};
    }
    __syncthreads();
    float bs = bias[DD];
    int x0 = (t & 15) * 4, yb = t >> 4;
    #pragma unroll
    for (int s = 0; s < 4; s++) {
        int y = yb + s * 16;
        float a0 = bs, a1 = bs, a2 = bs, a3 = bs;
        #pragma unroll
        for (int ky = 0; ky < 5; ky++) {
            int row = y + ky - 2;
            if (row < 0 || row >= 64) continue;
            const float* rp = &img[row * 72 + x0];
            float4 w0 = *(const float4*)rp;
            float4 w1 = *(const float4*)(rp + 4);
            float4 w2 = *(const float4*)(rp + 8);
            float win[12] = {w0.x, w0.y, w0.z, w0.w, w1.x, w1.y, w1.z, w1.w,
                             w2.x, w2.y, w2.z, w2.w};
            #pragma unroll
            for (int kx = 0; kx < 5; kx++) {
                float wt = wl[ky * 5 + kx];
                a0 += wt * win[2 + kx];
                a1 += wt * win[3 + kx];
                a2 += wt * win[4 + kx];
                a3 += wt * win[5 + kx];
            }
        }
        unsigned lo = pack2(a0, a1);
        unsigned hi = pack2(a2, a3);
        *(uint2*)(vloc + (size_t)gid * 4096 + y * 64 + x0) = (uint2){lo, hi};
    }
}

// ---- fused MFMA att + gate + GEMM2 v8 (R15-exact): 64-row tile, 512 threads ----
#define A2P 264
__global__ __launch_bounds__(512) void att_gemm2(
    const __hip_bfloat16* __restrict__ q16, const float* __restrict__ kv_mat2,
    const __hip_bfloat16* __restrict__ vloc, const __hip_bfloat16* __restrict__ g16,
    const __hip_bfloat16* __restrict__ Wt2, const float* __restrict__ bp,
    float* __restrict__ out)
{
    __shared__ __align__(16) unsigned short QA[64 * A2P];  // 33792 B
    __shared__ __align__(16) unsigned short Bs[256 * 32];  // 16384 B
    int t = threadIdx.x;
    int w = t >> 6, l = t & 63;
    int r0 = blockIdx.x * 64;
    int b = r0 >> 12, n0 = r0 & 4095;
    int lane15 = l & 15, quad = l >> 4;
    int h = w;  // one head per wave

    {
        const uint4* qsrc = (const uint4*)(q16 + (size_t)(r0 + (t >> 3)) * 256 + (t & 7) * 32);
        uint4* qdst = (uint4*)&QA[(t >> 3) * A2P + (t & 7) * 32];
        #pragma unroll
        for (int j = 0; j < 4; j++) qdst[j] = qsrc[j];
    }
    __syncthreads();

    short8 afr[4];
    #pragma unroll
    for (int m = 0; m < 4; m++)
        afr[m] = *(const short8*)&QA[(m * 16 + lane15) * A2P + h * 32 + quad * 8];

    short8 bfr[2];
    #pragma unroll
    for (int nt = 0; nt < 2; nt++) {
        const float4* kp = (const float4*)(kv_mat2 + (size_t)b * 8192 +
            (size_t)(nt * 16 + lane15) * 256 + h * 32 + quad * 8);
        float4 ka = kp[0], kb = kp[1];
        short8 bb;
        bb[0] = (short)f2bfbits(ka.x); bb[1] = (short)f2bfbits(ka.y);
        bb[2] = (short)f2bfbits(ka.z); bb[3] = (short)f2bfbits(ka.w);
        bb[4] = (short)f2bfbits(kb.x); bb[5] = (short)f2bfbits(kb.y);
        bb[6] = (short)f2bfbits(kb.z); bb[7] = (short)f2bfbits(kb.w);
        bfr[nt] = bb;
    }

    f32x4 ac[4][2];
    #pragma unroll
    for (int m = 0; m < 4; m++)
        #pragma unroll
        for (int nt = 0; nt < 2; nt++)
            ac[m][nt] = __builtin_amdgcn_mfma_f32_16x16x32_bf16(
                afr[m], bfr[nt], (f32x4){0.f, 0.f, 0.f, 0.f}, 0, 0, 0);

    #pragma unroll
    for (int m = 0; m < 4; m++) {
        #pragma unroll
        for (int nt = 0; nt < 2; nt++) {
            int col = h * 32 + nt * 16 + lane15;
            int rowb = m * 16 + quad * 4;
            size_t img = ((size_t)((b * 8 + (col & 7)) * 32 + (col >> 3))) * 4096 + n0 + rowb;
            uint2 vv = *(const uint2*)(vloc + img);
            float vl[4] = {bf_lo(vv.x), bf_hi(vv.x), bf_lo(vv.y), bf_hi(vv.y)};
            #pragma unroll
            for (int i = 0; i < 4; i++) {
                float gg = b2f(g16[(size_t)(r0 + rowb + i) * 256 + col]);
                float val = (ac[m][nt][i] + vl[i]) * gg;
                QA[(rowb + i) * A2P + col] = f2bfbits(val);
            }
        }
    }

    int wm = (w & 1) * 32, wn = (w >> 1) * 64;
    f32x4 acc2[2][4];
    #pragma unroll
    for (int mi = 0; mi < 2; mi++)
        #pragma unroll
        for (int ni = 0; ni < 4; ni++) acc2[mi][ni] = (f32x4){0.f, 0.f, 0.f, 0.f};

    for (int k0 = 0; k0 < 256; k0 += 32) {
        __syncthreads();
        #pragma unroll
        for (int j = 0; j < 2; j++) {
            int rowl = j * 128 + w * 16 + (l >> 2);
            int gchunk = (l & 3) ^ ((rowl >> 1) & 3);
            gl_lds16(&Wt2[(size_t)rowl * 256 + k0 + gchunk * 8],
                     &Bs[(j * 128 + w * 16) * 32]);
        }
        __syncthreads();
        short8 a[2], bb[4];
        #pragma unroll
        for (int mi = 0; mi < 2; mi++)
            a[mi] = *(const short8*)&QA[(wm + mi * 16 + lane15) * A2P + k0 + quad * 8];
        #pragma unroll
        for (int ni = 0; ni < 4; ni++) {
            int r = wn + ni * 16 + lane15;
            bb[ni] = *(const short8*)&Bs[r * 32 + ((quad ^ ((r >> 1) & 3)) << 3)];
        }
        #pragma unroll
        for (int mi = 0; mi < 2; mi++)
            #pragma unroll
            for (int ni = 0; ni < 4; ni++)
                acc2[mi][ni] = __builtin_amdgcn_mfma_f32_16x16x32_bf16(a[mi], bb[ni], acc2[mi][ni], 0, 0, 0);
    }

    #pragma unroll
    for (int mi = 0; mi < 2; mi++) {
        #pragma unroll
        for (int ni = 0; ni < 4; ni++) {
            int row = r0 + wm + mi * 16 + quad * 4;
            int col = wn + ni * 16 + lane15;
            float bv = bp[col];
            #pragma unroll
            for (int r = 0; r < 4; r++)
                out[(size_t)(row + r) * 256 + col] = acc2[mi][ni][r] + bv;
        }
    }
}

extern "C" void kernel_launch(void* const* d_in, const int* in_sizes, int n_in,
                              void* d_out, int out_size, void* d_ws, size_t ws_size,
                              hipStream_t stream) {
    const float* x      = (const float*)d_in[0];
    const float* W_qg   = (const float*)d_in[1];
    const float* W_kv   = (const float*)d_in[2];
    const float* W_proj = (const float*)d_in[3];
    const float* b_proj = (const float*)d_in[4];
    const float* dwc_w  = (const float*)d_in[5];
    const float* dwc_b  = (const float*)d_in[6];
    const float* pow_p  = (const float*)d_in[7];
    float* out = (float*)d_out;

    float* ws = (float*)d_ws;
    const size_t E = E_;
    __hip_bfloat16* q16  = (__hip_bfloat16*)ws;                  // E bf16
    __hip_bfloat16* k16  = (__hip_bfloat16*)(ws + E / 2);        // E bf16
    __hip_bfloat16* g16  = (__hip_bfloat16*)(ws + E);            // E bf16
    __hip_bfloat16* v16  = (__hip_bfloat16*)(ws + 3 * E / 2);    // E bf16
    __hip_bfloat16* xb   = (__hip_bfloat16*)(ws + 2 * E);        // E bf16
    __hip_bfloat16* vl16 = (__hip_bfloat16*)(ws + 5 * E / 2);    // E bf16
    float* kv_mat2 = ws + 3 * E;                                 // 65536 floats
    __hip_bfloat16* Wt1 = (__hip_bfloat16*)(kv_mat2 + 65536);    // 262144 bf16
    __hip_bfloat16* Wt2 = Wt1 + 262144;                          // 65536 bf16
    float* powers = (float*)(Wt2 + 65536);                       // 256 floats

    cvt_all<<<4096 + 81 + 64, 256, 0, stream>>>(x, W_qg, W_kv, W_proj, pow_p, xb, Wt1, Wt2, powers, kv_mat2);
    gemm1_mfma<<<1024, 256, 0, stream>>>(xb, Wt1, powers, q16, k16, g16, v16);
    kvconv_kernel<<<512 + 2048, 256, 0, stream>>>(k16, v16, kv_mat2, dwc_w, dwc_b, vl16);
    att_gemm2<<<512, 512, 0, stream>>>(q16, kv_mat2, vl16, g16, Wt2, b_proj, out);
}

// Round 17
// 169.676 us; speedup vs baseline: 1.3887x; 1.3887x over previous
//
#include <hip/hip_runtime.h>
#include <hip/hip_bf16.h>
#include <math.h>

#define B_ 8
#define N_ 4096
#define C_ 256
#define H_ 8
#define HD_ 32
#define BN_ (B_ * N_)  // 32768
#define E_ ((size_t)BN_ * C_)  // 8388608

typedef __attribute__((ext_vector_type(8))) short short8;
typedef __attribute__((ext_vector_type(4))) float f32x4;

__device__ __forceinline__ float b2f(__hip_bfloat16 x) { return __bfloat162float(x); }

__device__ __forceinline__ void gl_lds16(const void* gp, void* lp) {
    __builtin_amdgcn_global_load_lds(
        (const __attribute__((address_space(1))) unsigned int*)gp,
        (__attribute__((address_space(3))) unsigned int*)lp,
        16, 0, 0);
}

// raw v_log_f32 / v_exp_f32 (base-2), no ocml fixup
__device__ __forceinline__ float fast_abspow(float v, float p) {
    float av = fabsf(v);
    return (av > 0.f) ? __builtin_amdgcn_exp2f(p * __builtin_amdgcn_logf(av)) : 0.f;
}

__device__ __forceinline__ float bf_lo(unsigned u) { return __uint_as_float(u << 16); }
__device__ __forceinline__ float bf_hi(unsigned u) { return __uint_as_float(u & 0xffff0000u); }
__device__ __forceinline__ unsigned short f2bfbits(float f) {
    __hip_bfloat16 h = __float2bfloat16(f);
    return *(unsigned short*)&h;
}
__device__ __forceinline__ unsigned pack2(float lo, float hi) {
    return (unsigned)f2bfbits(lo) | ((unsigned)f2bfbits(hi) << 16);
}

// ---- merged converts: blocks [0,4096): x -> bf16 (vectorized); [4096,4177): weights+powers;
// ----                  blocks [4177, 4241): zero kv_mat2 (for atomic accumulation) ----
__global__ __launch_bounds__(256) void cvt_all(
    const float* __restrict__ x, const float* __restrict__ Wqg,
    const float* __restrict__ Wkv, const float* __restrict__ Wp,
    const float* __restrict__ pp,
    __hip_bfloat16* __restrict__ xb, __hip_bfloat16* __restrict__ Wt1,
    __hip_bfloat16* __restrict__ Wt2, float* __restrict__ powers,
    float* __restrict__ kv_mat2)
{
    int t = threadIdx.x;
    int bid0 = blockIdx.x;
    if (bid0 < 4096) {
        size_t i = ((size_t)bid0 * 256 + t) * 8;
        float4 a = *(const float4*)&x[i];
        float4 b = *(const float4*)&x[i + 4];
        uint4 o = {pack2(a.x, a.y), pack2(a.z, a.w), pack2(b.x, b.y), pack2(b.z, b.w)};
        *(uint4*)&xb[i] = o;
        return;
    }
    int bid = bid0 - 4096;
    if (bid == 80) {
        powers[t] = 1.0f + 4.0f / (1.0f + expf(-pp[t]));
        return;
    }
    if (bid >= 81) {
        ((float4*)kv_mat2)[(size_t)(bid - 81) * 256 + t] = (float4){0.f, 0.f, 0.f, 0.f};
        return;
    }
    __shared__ float tile[64][65];
    const float* src;
    __hip_bfloat16* dst;
    int scols, tr, tc, dn0;
    if (bid < 32)      { src = Wqg; scols = 512; tr = bid >> 3;        tc = bid & 7;        dst = Wt1; dn0 = tc * 64; }
    else if (bid < 64) { src = Wkv; scols = 512; tr = (bid - 32) >> 3; tc = (bid - 32) & 7; dst = Wt1; dn0 = 512 + tc * 64; }
    else               { src = Wp;  scols = 256; tr = (bid - 64) >> 2; tc = (bid - 64) & 3; dst = Wt2; dn0 = tc * 64; }
    int tx = t & 63, ty = t >> 6;
    #pragma unroll
    for (int i = 0; i < 16; i++) {
        int r = ty + i * 4;
        tile[r][tx] = src[(size_t)(tr * 64 + r) * scols + tc * 64 + tx];
    }
    __syncthreads();
    #pragma unroll
    for (int i = 0; i < 16; i++) {
        int n_local = ty + i * 4;
        dst[(size_t)(dn0 + n_local) * 256 + tr * 64 + tx] = __float2bfloat16(tile[tx][n_local]);
    }
}

// ---- GEMM1 v5 (R9-exact, best measured): 128x128 tile, BK=64, XCD chunk swizzle,
// ---- swizzled LDS staging, coalesced LDS-restaged epilogue. ----
__global__ __launch_bounds__(256) void gemm1_mfma(
    const __hip_bfloat16* __restrict__ xb, const __hip_bfloat16* __restrict__ Wt1,
    const float* __restrict__ powers,
    __hip_bfloat16* __restrict__ q16, __hip_bfloat16* __restrict__ k16,
    __hip_bfloat16* __restrict__ g16, __hip_bfloat16* __restrict__ v16)
{
    __shared__ __align__(16) unsigned short ABs[128 * 128];  // As[0:8K) Bs[8K:16K) shorts; reused as C-stage
    unsigned short* As = ABs;
    unsigned short* Bs = ABs + 128 * 64;
    int t = threadIdx.x;
    int w = t >> 6, l = t & 63;
    // XCD swizzle: nwg=2048, 8 XCDs, 256 blocks/XCD chunk (bijective)
    int bswz = (blockIdx.x & 7) * 256 + (blockIdx.x >> 3);
    int row0 = (bswz >> 3) * 128;
    int colb = bswz & 7;
    int col0 = colb * 128;
    int wm = (w >> 1) * 64, wn = (w & 1) * 64;
    int lane15 = l & 15, quad = l >> 4;
    int sr8 = l >> 3;                   // source row-within-band (0..7)
    int sc = ((l & 7) ^ sr8) * 8;       // pre-swizzled source chunk (shorts)
    int r7 = lane15 & 7;                // read-side row&7

    f32x4 acc[4][4];
    #pragma unroll
    for (int mi = 0; mi < 4; mi++)
        #pragma unroll
        for (int ni = 0; ni < 4; ni++) acc[mi][ni] = (f32x4){0.f, 0.f, 0.f, 0.f};

    for (int k0 = 0; k0 < 256; k0 += 64) {
        #pragma unroll
        for (int j = 0; j < 4; j++) {
            int rowl = j * 32 + w * 8 + sr8;
            gl_lds16(&xb[(size_t)(row0 + rowl) * 256 + k0 + sc],
                     &As[(j * 32 + w * 8) * 64]);
            gl_lds16(&Wt1[(size_t)(col0 + rowl) * 256 + k0 + sc],
                     &Bs[(j * 32 + w * 8) * 64]);
        }
        __syncthreads();
        #pragma unroll
        for (int kh = 0; kh < 2; kh++) {
            int cs_k = ((kh * 4 + quad) ^ r7) * 8;
            short8 a[4], b[4];
            #pragma unroll
            for (int mi = 0; mi < 4; mi++)
                a[mi] = *(const short8*)&As[(wm + mi * 16 + lane15) * 64 + cs_k];
            #pragma unroll
            for (int ni = 0; ni < 4; ni++)
                b[ni] = *(const short8*)&Bs[(wn + ni * 16 + lane15) * 64 + cs_k];
            #pragma unroll
            for (int mi = 0; mi < 4; mi++)
                #pragma unroll
                for (int ni = 0; ni < 4; ni++)
                    acc[mi][ni] = __builtin_amdgcn_mfma_f32_16x16x32_bf16(a[mi], b[ni], acc[mi][ni], 0, 0, 0);
        }
        __syncthreads();
    }

    int region = colb >> 1;  // 0:q 1:g 2:k 3:v
    bool dopow = (region == 0) || (region == 2);
    __hip_bfloat16* dst = (region == 0) ? q16 : (region == 1) ? g16 : (region == 2) ? k16 : v16;
    int cbase = col0 & 255;
    #pragma unroll
    for (int mi = 0; mi < 4; mi++) {
        #pragma unroll
        for (int ni = 0; ni < 4; ni++) {
            int rowb = wm + mi * 16 + quad * 4;
            int coll = wn + ni * 16 + lane15;
            float p = powers[cbase + coll];
            int cchunk = coll >> 3, cin = coll & 7;
            #pragma unroll
            for (int r = 0; r < 4; r++) {
                int rl = rowb + r;
                float v = acc[mi][ni][r];
                float o = dopow ? fast_abspow(v, p) : v;
                ABs[rl * 128 + ((cchunk ^ (rl & 15)) << 3) + cin] = f2bfbits(o);
            }
        }
    }
    __syncthreads();
    #pragma unroll
    for (int j = 0; j < 8; j++) {
        int g = j * 256 + t;
        int rl = g >> 4, chunk = g & 15;
        uint4 vv = *(const uint4*)&ABs[rl * 128 + ((chunk ^ (rl & 15)) << 3)];
        *(uint4*)&dst[(size_t)(row0 + rl) * 256 + cbase + chunk * 8] = vv;
    }
}

// ---- fused kvmat_mfma (blocks 0..511) + depthwise conv (blocks 512..2559) (R9-exact) ----
__global__ __launch_bounds__(256) void kvconv_kernel(
    const __hip_bfloat16* __restrict__ k16, const __hip_bfloat16* __restrict__ v16,
    float* __restrict__ kv_mat2,
    const float* __restrict__ w, const float* __restrict__ bias,
    __hip_bfloat16* __restrict__ vloc)
{
    __shared__ __align__(16) unsigned char smraw[18560];
    int t = threadIdx.x;

    if (blockIdx.x < 512) {
        unsigned short (*KV)[32][136] = (unsigned short (*)[32][136])smraw;  // 17408 B
        int w_ = t >> 6, l = t & 63;
        int lane15 = l & 15, quad = l >> 4;
        int bid = blockIdx.x;
        int pair = bid >> 3, seg = bid & 7;
        int b = pair >> 3, h = pair & 7;
        int nloc = t & 127, cs = (t >> 7) * 16;

        f32x4 acc[2][2];
        #pragma unroll
        for (int di = 0; di < 2; di++)
            #pragma unroll
            for (int ei = 0; ei < 2; ei++) acc[di][ei] = (f32x4){0.f, 0.f, 0.f, 0.f};

        const size_t base = (size_t)b * N_ * 256 + h * 32 + cs;
        for (int c4 = 0; c4 < 4; c4++) {
            int n0 = seg * 512 + c4 * 128;
            const uint4* kp = (const uint4*)(k16 + base + (size_t)(n0 + nloc) * 256);
            uint4 ka = kp[0], kb = kp[1];
            const uint4* vp = (const uint4*)(v16 + base + (size_t)(n0 + nloc) * 256);
            uint4 va = vp[0], vb = vp[1];
            __syncthreads();
            unsigned kw[8] = {ka.x, ka.y, ka.z, ka.w, kb.x, kb.y, kb.z, kb.w};
            unsigned vw[8] = {va.x, va.y, va.z, va.w, vb.x, vb.y, vb.z, vb.w};
            #pragma unroll
            for (int j = 0; j < 8; j++) {
                KV[0][cs + 2 * j][nloc]     = (unsigned short)(kw[j] & 0xffffu);
                KV[0][cs + 2 * j + 1][nloc] = (unsigned short)(kw[j] >> 16);
                KV[1][cs + 2 * j][nloc]     = (unsigned short)(vw[j] & 0xffffu);
                KV[1][cs + 2 * j + 1][nloc] = (unsigned short)(vw[j] >> 16);
            }
            __syncthreads();
            int nb = w_ * 32 + quad * 8;
            short8 a[2], bb[2];
            #pragma unroll
            for (int di = 0; di < 2; di++)
                a[di] = *(const short8*)&KV[0][di * 16 + lane15][nb];
            #pragma unroll
            for (int ei = 0; ei < 2; ei++)
                bb[ei] = *(const short8*)&KV[1][ei * 16 + lane15][nb];
            #pragma unroll
            for (int di = 0; di < 2; di++)
                #pragma unroll
                for (int ei = 0; ei < 2; ei++)
                    acc[di][ei] = __builtin_amdgcn_mfma_f32_16x16x32_bf16(a[di], bb[ei], acc[di][ei], 0, 0, 0);
        }

        __syncthreads();
        float* red = (float*)smraw;  // [4][32][33] f32 = 16896 B
        #pragma unroll
        for (int di = 0; di < 2; di++)
            #pragma unroll
            for (int ei = 0; ei < 2; ei++) {
                int e = ei * 16 + lane15;
                #pragma unroll
                for (int r = 0; r < 4; r++) {
                    int d = di * 16 + quad * 4 + r;
                    red[w_ * 1056 + e * 33 + d] = acc[di][ei][r];
                }
            }
        __syncthreads();
        #pragma unroll
        for (int j = 0; j < 4; j++) {
            int o = j * 256 + t;
            int e = o >> 5, d = o & 31;
            float s = red[e * 33 + d] + red[1056 + e * 33 + d]
                    + red[2112 + e * 33 + d] + red[3168 + e * 33 + d];
            atomicAdd(&kv_mat2[(size_t)b * 8192 + e * 256 + h * 32 + d], s);
        }
        return;
    }

    // ---- depthwise 5x5 conv body ----
    float* img = (float*)smraw;                  // 64*72 floats = 18432 B
    float* wl  = (float*)(smraw + 18432);        // 25 floats
    int gid = blockIdx.x - 512;
    int DD = gid & 31;
    if (t < 128) {
        int row = t >> 1, side = (t & 1) * 68;
        *(float4*)&img[row * 72 + side] = (float4){0.f, 0.f, 0.f, 0.f};
    }
    if (t < 25) wl[t] = w[DD * 25 + t];
    {
        int row = t >> 2, colb = (t & 3) * 16;
        const uint4* src = (const uint4*)(v16 + (size_t)gid * 4096 + row * 64 + colb);
        uint4 u0 = src[0], u1 = src[1];
        float4* d = (float4*)&img[row * 72 + 4 + colb];
        d[0] = (float4){bf_lo(u0.x), bf_hi(u0.x), bf_lo(u0.y), bf_hi(u0.y)};
        d[1] = (float4){bf_lo(u0.z), bf_hi(u0.z), bf_lo(u0.w), bf_hi(u0.w)};
        d[2] = (float4){bf_lo(u1.x), bf_hi(u1.x), bf_lo(u1.y), bf_hi(u1.y)};
        d[3] = (float4){bf_lo(u1.z), bf_hi(u1.z), bf_lo(u1.w), bf_hi(u1.w)};
    }
    __syncthreads();
    float bs = bias[DD];
    int x0 = (t & 15) * 4, yb = t >> 4;
    #pragma unroll
    for (int s = 0; s < 4; s++) {
        int y = yb + s * 16;
        float a0 = bs, a1 = bs, a2 = bs, a3 = bs;
        #pragma unroll
        for (int ky = 0; ky < 5; ky++) {
            int row = y + ky - 2;
            if (row < 0 || row >= 64) continue;
            const float* rp = &img[row * 72 + x0];
            float4 w0 = *(const float4*)rp;
            float4 w1 = *(const float4*)(rp + 4);
            float4 w2 = *(const float4*)(rp + 8);
            float win[12] = {w0.x, w0.y, w0.z, w0.w, w1.x, w1.y, w1.z, w1.w,
                             w2.x, w2.y, w2.z, w2.w};
            #pragma unroll
            for (int kx = 0; kx < 5; kx++) {
                float wt = wl[ky * 5 + kx];
                a0 += wt * win[2 + kx];
                a1 += wt * win[3 + kx];
                a2 += wt * win[4 + kx];
                a3 += wt * win[5 + kx];
            }
        }
        unsigned lo = pack2(a0, a1);
        unsigned hi = pack2(a2, a3);
        *(uint2*)(vloc + (size_t)gid * 4096 + y * 64 + x0) = (uint2){lo, hi};
    }
}

// ---- fused MFMA att + gate + GEMM2 v8 (R15-exact): 64-row tile, 512 threads ----
#define A2P 264
__global__ __launch_bounds__(512) void att_gemm2(
    const __hip_bfloat16* __restrict__ q16, const float* __restrict__ kv_mat2,
    const __hip_bfloat16* __restrict__ vloc, const __hip_bfloat16* __restrict__ g16,
    const __hip_bfloat16* __restrict__ Wt2, const float* __restrict__ bp,
    float* __restrict__ out)
{
    __shared__ __align__(16) unsigned short QA[64 * A2P];  // 33792 B
    __shared__ __align__(16) unsigned short Bs[256 * 32];  // 16384 B
    int t = threadIdx.x;
    int w = t >> 6, l = t & 63;
    int r0 = blockIdx.x * 64;
    int b = r0 >> 12, n0 = r0 & 4095;
    int lane15 = l & 15, quad = l >> 4;
    int h = w;  // one head per wave

    {
        const uint4* qsrc = (const uint4*)(q16 + (size_t)(r0 + (t >> 3)) * 256 + (t & 7) * 32);
        uint4* qdst = (uint4*)&QA[(t >> 3) * A2P + (t & 7) * 32];
        #pragma unroll
        for (int j = 0; j < 4; j++) qdst[j] = qsrc[j];
    }
    __syncthreads();

    short8 afr[4];
    #pragma unroll
    for (int m = 0; m < 4; m++)
        afr[m] = *(const short8*)&QA[(m * 16 + lane15) * A2P + h * 32 + quad * 8];

    short8 bfr[2];
    #pragma unroll
    for (int nt = 0; nt < 2; nt++) {
        const float4* kp = (const float4*)(kv_mat2 + (size_t)b * 8192 +
            (size_t)(nt * 16 + lane15) * 256 + h * 32 + quad * 8);
        float4 ka = kp[0], kb = kp[1];
        short8 bb;
        bb[0] = (short)f2bfbits(ka.x); bb[1] = (short)f2bfbits(ka.y);
        bb[2] = (short)f2bfbits(ka.z); bb[3] = (short)f2bfbits(ka.w);
        bb[4] = (short)f2bfbits(kb.x); bb[5] = (short)f2bfbits(kb.y);
        bb[6] = (short)f2bfbits(kb.z); bb[7] = (short)f2bfbits(kb.w);
        bfr[nt] = bb;
    }

    f32x4 ac[4][2];
    #pragma unroll
    for (int m = 0; m < 4; m++)
        #pragma unroll
        for (int nt = 0; nt < 2; nt++)
            ac[m][nt] = __builtin_amdgcn_mfma_f32_16x16x32_bf16(
                afr[m], bfr[nt], (f32x4){0.f, 0.f, 0.f, 0.f}, 0, 0, 0);

    #pragma unroll
    for (int m = 0; m < 4; m++) {
        #pragma unroll
        for (int nt = 0; nt < 2; nt++) {
            int col = h * 32 + nt * 16 + lane15;
            int rowb = m * 16 + quad * 4;
            size_t img = ((size_t)((b * 8 + (col & 7)) * 32 + (col >> 3))) * 4096 + n0 + rowb;
            uint2 vv = *(const uint2*)(vloc + img);
            float vl[4] = {bf_lo(vv.x), bf_hi(vv.x), bf_lo(vv.y), bf_hi(vv.y)};
            #pragma unroll
            for (int i = 0; i < 4; i++) {
                float gg = b2f(g16[(size_t)(r0 + rowb + i) * 256 + col]);
                float val = (ac[m][nt][i] + vl[i]) * gg;
                QA[(rowb + i) * A2P + col] = f2bfbits(val);
            }
        }
    }

    int wm = (w & 1) * 32, wn = (w >> 1) * 64;
    f32x4 acc2[2][4];
    #pragma unroll
    for (int mi = 0; mi < 2; mi++)
        #pragma unroll
        for (int ni = 0; ni < 4; ni++) acc2[mi][ni] = (f32x4){0.f, 0.f, 0.f, 0.f};

    for (int k0 = 0; k0 < 256; k0 += 32) {
        __syncthreads();
        #pragma unroll
        for (int j = 0; j < 2; j++) {
            int rowl = j * 128 + w * 16 + (l >> 2);
            int gchunk = (l & 3) ^ ((rowl >> 1) & 3);
            gl_lds16(&Wt2[(size_t)rowl * 256 + k0 + gchunk * 8],
                     &Bs[(j * 128 + w * 16) * 32]);
        }
        __syncthreads();
        short8 a[2], bb[4];
        #pragma unroll
        for (int mi = 0; mi < 2; mi++)
            a[mi] = *(const short8*)&QA[(wm + mi * 16 + lane15) * A2P + k0 + quad * 8];
        #pragma unroll
        for (int ni = 0; ni < 4; ni++) {
            int r = wn + ni * 16 + lane15;
            bb[ni] = *(const short8*)&Bs[r * 32 + ((quad ^ ((r >> 1) & 3)) << 3)];
        }
        #pragma unroll
        for (int mi = 0; mi < 2; mi++)
            #pragma unroll
            for (int ni = 0; ni < 4; ni++)
                acc2[mi][ni] = __builtin_amdgcn_mfma_f32_16x16x32_bf16(a[mi], bb[ni], acc2[mi][ni], 0, 0, 0);
    }

    #pragma unroll
    for (int mi = 0; mi < 2; mi++) {
        #pragma unroll
        for (int ni = 0; ni < 4; ni++) {
            int row = r0 + wm + mi * 16 + quad * 4;
            int col = wn + ni * 16 + lane15;
            float bv = bp[col];
            #pragma unroll
            for (int r = 0; r < 4; r++)
                out[(size_t)(row + r) * 256 + col] = acc2[mi][ni][r] + bv;
        }
    }
}

extern "C" void kernel_launch(void* const* d_in, const int* in_sizes, int n_in,
                              void* d_out, int out_size, void* d_ws, size_t ws_size,
                              hipStream_t stream) {
    const float* x      = (const float*)d_in[0];
    const float* W_qg   = (const float*)d_in[1];
    const float* W_kv   = (const float*)d_in[2];
    const float* W_proj = (const float*)d_in[3];
    const float* b_proj = (const float*)d_in[4];
    const float* dwc_w  = (const float*)d_in[5];
    const float* dwc_b  = (const float*)d_in[6];
    const float* pow_p  = (const float*)d_in[7];
    float* out = (float*)d_out;

    float* ws = (float*)d_ws;
    const size_t E = E_;
    __hip_bfloat16* q16  = (__hip_bfloat16*)ws;                  // E bf16
    __hip_bfloat16* k16  = (__hip_bfloat16*)(ws + E / 2);        // E bf16
    __hip_bfloat16* g16  = (__hip_bfloat16*)(ws + E);            // E bf16
    __hip_bfloat16* v16  = (__hip_bfloat16*)(ws + 3 * E / 2);    // E bf16
    __hip_bfloat16* xb   = (__hip_bfloat16*)(ws + 2 * E);        // E bf16
    __hip_bfloat16* vl16 = (__hip_bfloat16*)(ws + 5 * E / 2);    // E bf16
    float* kv_mat2 = ws + 3 * E;                                 // 65536 floats
    __hip_bfloat16* Wt1 = (__hip_bfloat16*)(kv_mat2 + 65536);    // 262144 bf16
    __hip_bfloat16* Wt2 = Wt1 + 262144;                          // 65536 bf16
    float* powers = (float*)(Wt2 + 65536);                       // 256 floats

    cvt_all<<<4096 + 81 + 64, 256, 0, stream>>>(x, W_qg, W_kv, W_proj, pow_p, xb, Wt1, Wt2, powers, kv_mat2);
    gemm1_mfma<<<2048, 256, 0, stream>>>(xb, Wt1, powers, q16, k16, g16, v16);
    kvconv_kernel<<<512 + 2048, 256, 0, stream>>>(k16, v16, kv_mat2, dwc_w, dwc_b, vl16);
    att_gemm2<<<512, 512, 0, stream>>>(q16, kv_mat2, vl16, g16, Wt2, b_proj, out);
}